// Round 1
// baseline (502.340 us; speedup 1.0000x reference)
//
#include <hip/hip_runtime.h>
#include <hip/hip_bf16.h>
#include <cstddef>

#define B_ 4
#define L_ 2305
#define LSEQ 2304
#define NCHUNK 37
#define CHUNK 64

static __device__ __forceinline__ float sigmoidf_(float x){ return 1.f/(1.f+__expf(-x)); }

// ---------------- K0: build seq (pixel_shuffle + global token) ----------------
__global__ __launch_bounds__(256) void k_build_seq(const float* __restrict__ x,
                                                   const float* __restrict__ gtok,
                                                   float* __restrict__ seq){
  int gid = blockIdx.x*256 + threadIdx.x;           // < B*L*256
  int c = gid & 255;
  int m = gid >> 8;
  int b = m / L_;
  int t = m - b*L_;
  float v;
  if (t == 0) {
    v = gtok[c];
  } else {
    int tt = t - 1;
    int p = tt / 48, q = tt - (tt/48)*48;
    int ch = (c<<2) + ((p&1)<<1) + (q&1);
    v = x[((size_t)(b*1024 + ch)*24 + (p>>1))*24 + (q>>1)];
  }
  seq[gid] = v;
}

// ---------------- K1: in_proj GEMM (M=9220,K=256,N=1024) -> u,z ----------------
__global__ __launch_bounds__(256) void k_gemm_in(const float* __restrict__ Aseq,
                                                 const float* __restrict__ W,
                                                 float* __restrict__ u,
                                                 float* __restrict__ z){
  __shared__ float As[16][68];
  __shared__ float Bs[16][68];
  int tid = threadIdx.x;
  int row0 = blockIdx.x*64, col0 = blockIdx.y*64;
  int lr = tid >> 2;            // 0..63
  int lk = (tid & 3) << 2;      // 0,4,8,12
  int tr = tid >> 4, tc = tid & 15;
  float acc[4][4] = {};
  int arow = row0 + lr;
  bool aok = arow < (B_*L_);
  const float* ap = Aseq + (size_t)(aok ? arow : 0)*256 + lk;
  const float* wp = W + (size_t)(col0 + lr)*256 + lk;
  for (int k0 = 0; k0 < 256; k0 += 16) {
    float4 av = aok ? *(const float4*)(ap + k0) : make_float4(0.f,0.f,0.f,0.f);
    float4 bv = *(const float4*)(wp + k0);
    As[lk+0][lr]=av.x; As[lk+1][lr]=av.y; As[lk+2][lr]=av.z; As[lk+3][lr]=av.w;
    Bs[lk+0][lr]=bv.x; Bs[lk+1][lr]=bv.y; Bs[lk+2][lr]=bv.z; Bs[lk+3][lr]=bv.w;
    __syncthreads();
    #pragma unroll
    for (int kk = 0; kk < 16; kk++) {
      float4 a4 = *(const float4*)&As[kk][tr<<2];
      float4 b4 = *(const float4*)&Bs[kk][tc<<2];
      float ar[4] = {a4.x,a4.y,a4.z,a4.w};
      float br[4] = {b4.x,b4.y,b4.z,b4.w};
      #pragma unroll
      for (int i=0;i<4;i++){
        #pragma unroll
        for (int j=0;j<4;j++) acc[i][j] += ar[i]*br[j];
      }
    }
    __syncthreads();
  }
  #pragma unroll
  for (int i=0;i<4;i++){
    int r = row0 + (tr<<2) + i;
    if (r < B_*L_){
      #pragma unroll
      for (int j=0;j<4;j++){
        int cc = col0 + (tc<<2) + j;
        float v = acc[i][j];
        if (cc < 512) u[(size_t)r*512 + cc] = v;
        else          z[(size_t)r*512 + cc - 512] = v;
      }
    }
  }
}

// ---------------- K2: depthwise causal conv(4) + silu ----------------
__global__ __launch_bounds__(256) void k_conv(const float* __restrict__ u,
                                              const float* __restrict__ cw,
                                              const float* __restrict__ cb,
                                              float* __restrict__ uc){
  int gid = blockIdx.x*256 + threadIdx.x;           // < B*L*512
  int d = gid & 511;
  int m = gid >> 9;
  int b = m / L_;
  int l = m - b*L_;
  float4 w = *(const float4*)&cw[d<<2];
  float acc = cb[d];
  const float* up = u + (size_t)m*512 + d;
  if (l >= 3) acc += up[-3*512]*w.x;
  if (l >= 2) acc += up[-2*512]*w.y;
  if (l >= 1) acc += up[-1*512]*w.z;
  acc += up[0]*w.w;
  uc[gid] = acc * sigmoidf_(acc);
}

// ---------------- transpose x_proj_w (48x512) -> wT (512x48) ----------------
__global__ __launch_bounds__(256) void k_transpose_w(const float* __restrict__ xw,
                                                     float* __restrict__ wT){
  int gid = blockIdx.x*256 + threadIdx.x;           // < 48*512
  int j = gid >> 9; int k = gid & 511;
  wT[k*48 + j] = xw[gid];
}

// ---------------- K3: x_dbl = uc @ x_proj_w^T (K=512, N=48) ----------------
__global__ __launch_bounds__(256) void k_xdbl(const float* __restrict__ uc,
                                              const float* __restrict__ wT,
                                              float* __restrict__ xdbl){
  int wave = threadIdx.x >> 6, lane = threadIdx.x & 63;
  int m0 = (blockIdx.x*4 + wave)*8;
  if (m0 >= B_*L_) return;
  int rows = min(8, B_*L_ - m0);
  const float* rp[8];
  #pragma unroll
  for (int r=0;r<8;r++) rp[r] = uc + (size_t)min(m0+r, B_*L_-1)*512;
  float acc[8] = {};
  for (int k = 0; k < 512; k++) {
    float w = (lane < 48) ? wT[k*48 + lane] : 0.f;
    #pragma unroll
    for (int r=0;r<8;r++) acc[r] += w * rp[r][k];
  }
  if (lane < 48) {
    for (int r=0;r<rows;r++) xdbl[(size_t)(m0+r)*48 + lane] = acc[r];
  }
}

// ---------------- K4: dt = softplus(x_dbl[:, :16] @ dt_proj_w^T + b) ----------------
__global__ __launch_bounds__(256) void k_dt(const float* __restrict__ xdbl,
                                            const float* __restrict__ dpw,
                                            const float* __restrict__ dpb,
                                            float* __restrict__ dt){
  __shared__ float xr[16];
  int m = blockIdx.x;
  int d = blockIdx.y*256 + threadIdx.x;
  if (threadIdx.x < 16) xr[threadIdx.x] = xdbl[(size_t)m*48 + threadIdx.x];
  __syncthreads();
  const float4* wp = (const float4*)&dpw[d<<4];
  float4 w0 = wp[0], w1 = wp[1], w2 = wp[2], w3 = wp[3];
  float acc = dpb[d];
  acc += w0.x*xr[0]  + w0.y*xr[1]  + w0.z*xr[2]  + w0.w*xr[3];
  acc += w1.x*xr[4]  + w1.y*xr[5]  + w1.z*xr[6]  + w1.w*xr[7];
  acc += w2.x*xr[8]  + w2.y*xr[9]  + w2.z*xr[10] + w2.w*xr[11];
  acc += w3.x*xr[12] + w3.y*xr[13] + w3.z*xr[14] + w3.w*xr[15];
  float v = (acc > 20.f) ? acc : log1pf(__expf(acc));
  dt[(size_t)m*512 + d] = v;
}

// ---------------- K5a: chunk-local scan (h_in = 0) ----------------
__global__ __launch_bounds__(128) void k_scan1(const float* __restrict__ dt,
                                               const float* __restrict__ uc,
                                               const float* __restrict__ xdbl,
                                               const float* __restrict__ A_log,
                                               float* __restrict__ sumdt,
                                               float* __restrict__ hend){
  __shared__ float Bsh[CHUNK*16];
  int c = blockIdx.x, b = blockIdx.y, qr = blockIdx.z;
  int d = qr*128 + threadIdx.x;
  int l0 = c*CHUNK;
  int len = min(CHUNK, L_ - l0);
  for (int i = threadIdx.x; i < len*16; i += 128) {
    int ll = i >> 4, n = i & 15;
    Bsh[i] = xdbl[(size_t)(b*L_ + l0 + ll)*48 + 16 + n];
  }
  __syncthreads();
  float A[16];
  #pragma unroll
  for (int g=0; g<4; g++){
    float4 al = *(const float4*)&A_log[(size_t)(d<<4) + g*4];
    A[g*4+0] = -__expf(al.x); A[g*4+1] = -__expf(al.y);
    A[g*4+2] = -__expf(al.z); A[g*4+3] = -__expf(al.w);
  }
  float h[16];
  #pragma unroll
  for (int n=0;n<16;n++) h[n]=0.f;
  float sd = 0.f;
  const float* dtp = dt + (size_t)(b*L_ + l0)*512 + d;
  const float* up  = uc + (size_t)(b*L_ + l0)*512 + d;
  for (int ll=0; ll<len; ll++){
    float dtv = dtp[(size_t)ll*512];
    float uv  = up[(size_t)ll*512];
    sd += dtv;
    float du = dtv*uv;
    const float* bl = &Bsh[ll*16];
    #pragma unroll
    for (int n=0;n<16;n++) h[n] = __expf(dtv*A[n])*h[n] + du*bl[n];
  }
  size_t base = (size_t)(b*512 + d)*NCHUNK + c;
  sumdt[base] = sd;
  #pragma unroll
  for (int n=0;n<16;n++) hend[base*16 + n] = h[n];
}

// ---------------- K5b: inter-chunk scan (37 steps per (b,d)) ----------------
__global__ __launch_bounds__(256) void k_scan2(const float* __restrict__ sumdt,
                                               const float* __restrict__ hend,
                                               const float* __restrict__ A_log,
                                               float* __restrict__ Hc){
  int idx = blockIdx.x*256 + threadIdx.x;   // < 2048
  int b = idx >> 9, d = idx & 511;
  float A[16];
  #pragma unroll
  for (int g=0; g<4; g++){
    float4 al = *(const float4*)&A_log[(size_t)(d<<4) + g*4];
    A[g*4+0] = -__expf(al.x); A[g*4+1] = -__expf(al.y);
    A[g*4+2] = -__expf(al.z); A[g*4+3] = -__expf(al.w);
  }
  float H[16];
  #pragma unroll
  for (int n=0;n<16;n++) H[n]=0.f;
  size_t rb = (size_t)(b*512+d)*NCHUNK;
  for (int c=0;c<NCHUNK;c++){
    size_t base = (rb + c)*16;
    #pragma unroll
    for (int n=0;n<16;n++) Hc[base+n] = H[n];
    float s = sumdt[rb + c];
    #pragma unroll
    for (int n=0;n<16;n++) H[n] = __expf(A[n]*s)*H[n] + hend[base+n];
  }
}

// ---------------- K5c: chunk replay with carry + fused epilogue ----------------
__global__ __launch_bounds__(128) void k_scan3(const float* __restrict__ dt,
                                               const float* __restrict__ uc,
                                               const float* __restrict__ zb,
                                               const float* __restrict__ xdbl,
                                               const float* __restrict__ A_log,
                                               const float* __restrict__ Dp,
                                               const float* __restrict__ Hc,
                                               float* __restrict__ y){
  __shared__ float Bsh[CHUNK*16];
  __shared__ float Csh[CHUNK*16];
  int c = blockIdx.x, b = blockIdx.y, qr = blockIdx.z;
  int d = qr*128 + threadIdx.x;
  int l0 = c*CHUNK;
  int len = min(CHUNK, L_ - l0);
  for (int i = threadIdx.x; i < len*16; i += 128) {
    int ll = i >> 4, n = i & 15;
    size_t rowb = (size_t)(b*L_ + l0 + ll)*48;
    Bsh[i] = xdbl[rowb + 16 + n];
    Csh[i] = xdbl[rowb + 32 + n];
  }
  __syncthreads();
  float A[16];
  #pragma unroll
  for (int g=0; g<4; g++){
    float4 al = *(const float4*)&A_log[(size_t)(d<<4) + g*4];
    A[g*4+0] = -__expf(al.x); A[g*4+1] = -__expf(al.y);
    A[g*4+2] = -__expf(al.z); A[g*4+3] = -__expf(al.w);
  }
  float h[16];
  size_t cb = ((size_t)(b*512+d)*NCHUNK + c)*16;
  #pragma unroll
  for (int n=0;n<16;n++) h[n] = Hc[cb+n];
  float Dd = Dp[d];
  size_t off = (size_t)(b*L_ + l0)*512 + d;
  for (int ll=0; ll<len; ll++){
    float dtv = dt[off + (size_t)ll*512];
    float uv  = uc[off + (size_t)ll*512];
    float du = dtv*uv;
    float yv = 0.f;
    const float* bl = &Bsh[ll*16];
    const float* cl = &Csh[ll*16];
    #pragma unroll
    for (int n=0;n<16;n++){
      h[n] = __expf(dtv*A[n])*h[n] + du*bl[n];
      yv += h[n]*cl[n];
    }
    float zv = zb[off + (size_t)ll*512];
    y[off + (size_t)ll*512] = (yv + uv*Dd) * (zv * sigmoidf_(zv));
  }
}

// ---------------- K6: out_proj GEMM (M=9216,K=512,N=256), skip token 0 ----------------
__global__ __launch_bounds__(256) void k_gemm_out(const float* __restrict__ Y,
                                                  const float* __restrict__ W,
                                                  float* __restrict__ tmp){
  __shared__ float As[16][68];
  __shared__ float Bs[16][68];
  int tid = threadIdx.x;
  int row0 = blockIdx.x*64, col0 = blockIdx.y*64;
  int lr = tid >> 2, lk = (tid&3)<<2, tr = tid>>4, tc = tid&15;
  int r = row0 + lr;                        // < 9216 always
  int b = r / LSEQ;
  int arow = b*L_ + 1 + (r - b*LSEQ);
  const float* ap = Y + (size_t)arow*512 + lk;
  const float* wp = W + (size_t)(col0 + lr)*512 + lk;
  float acc[4][4] = {};
  for (int k0=0; k0<512; k0+=16){
    float4 av = *(const float4*)(ap + k0);
    float4 bv = *(const float4*)(wp + k0);
    As[lk+0][lr]=av.x; As[lk+1][lr]=av.y; As[lk+2][lr]=av.z; As[lk+3][lr]=av.w;
    Bs[lk+0][lr]=bv.x; Bs[lk+1][lr]=bv.y; Bs[lk+2][lr]=bv.z; Bs[lk+3][lr]=bv.w;
    __syncthreads();
    #pragma unroll
    for (int kk = 0; kk < 16; kk++) {
      float4 a4 = *(const float4*)&As[kk][tr<<2];
      float4 b4 = *(const float4*)&Bs[kk][tc<<2];
      float ar[4] = {a4.x,a4.y,a4.z,a4.w};
      float br[4] = {b4.x,b4.y,b4.z,b4.w};
      #pragma unroll
      for (int i=0;i<4;i++){
        #pragma unroll
        for (int j=0;j<4;j++) acc[i][j] += ar[i]*br[j];
      }
    }
    __syncthreads();
  }
  #pragma unroll
  for (int i=0;i<4;i++){
    size_t rr = (size_t)(row0 + (tr<<2) + i)*256 + col0 + (tc<<2);
    #pragma unroll
    for (int j=0;j<4;j++) tmp[rr + j] = acc[i][j];
  }
}

// ---------------- K7: pixel_unshuffle scatter (coalesced writes) ----------------
__global__ __launch_bounds__(256) void k_scatter(const float* __restrict__ tmp,
                                                 float* __restrict__ out){
  int gid = blockIdx.x*256 + threadIdx.x;   // < 4*1024*24*24
  int w = gid % 24;
  int t1 = gid / 24;
  int h = t1 % 24;
  int t2 = t1 / 24;
  int co = t2 & 1023;
  int b = t2 >> 10;
  int c = co >> 2;
  int i = (co >> 1) & 1;
  int j = co & 1;
  int p = (h<<1) + i, q = (w<<1) + j;
  int t = p*48 + q;
  out[gid] = tmp[(size_t)(b*LSEQ + t)*256 + c];
}

extern "C" void kernel_launch(void* const* d_in, const int* in_sizes, int n_in,
                              void* d_out, int out_size, void* d_ws, size_t ws_size,
                              hipStream_t stream) {
  const float* x          = (const float*)d_in[0];
  const float* gtok       = (const float*)d_in[1];
  const float* in_proj_w  = (const float*)d_in[2];
  const float* conv_w     = (const float*)d_in[3];
  const float* conv_b     = (const float*)d_in[4];
  const float* x_proj_w   = (const float*)d_in[5];
  const float* dt_proj_w  = (const float*)d_in[6];
  const float* dt_proj_b  = (const float*)d_in[7];
  const float* A_log      = (const float*)d_in[8];
  const float* Dp         = (const float*)d_in[9];
  const float* out_proj_w = (const float*)d_in[10];

  float* ws = (float*)d_ws;
  const size_t ML = (size_t)B_*L_;          // 9220
  float* seq  = ws;                          // ML*256
  float* ubuf = seq  + ML*256;               // ML*512
  float* zbuf = ubuf + ML*512;               // ML*512
  float* ucb  = zbuf + ML*512;               // ML*512
  float* xdbl = ucb  + ML*512;               // ML*48
  float* wT   = xdbl + ML*48;                // 512*48
  float* sumdt= wT   + 512*48;               // B*512*NCHUNK
  float* hend = sumdt+ (size_t)B_*512*NCHUNK;       // *16
  float* Hc   = hend + (size_t)B_*512*NCHUNK*16;    // *16
  float* ybuf = Hc   + (size_t)B_*512*NCHUNK*16;    // ML*512
  float* dtb  = ubuf;   // reuse: pre-conv u dead after k_conv
  float* tmp  = seq;    // reuse: seq dead after k_gemm_in

  k_build_seq <<<9220, 256, 0, stream>>>(x, gtok, seq);
  k_gemm_in   <<<dim3(145,16), 256, 0, stream>>>(seq, in_proj_w, ubuf, zbuf);
  k_conv      <<<18440, 256, 0, stream>>>(ubuf, conv_w, conv_b, ucb);
  k_transpose_w<<<96, 256, 0, stream>>>(x_proj_w, wT);
  k_xdbl      <<<289, 256, 0, stream>>>(ucb, wT, xdbl);
  k_dt        <<<dim3(9220,2), 256, 0, stream>>>(xdbl, dt_proj_w, dt_proj_b, dtb);
  k_scan1     <<<dim3(NCHUNK,4,4), 128, 0, stream>>>(dtb, ucb, xdbl, A_log, sumdt, hend);
  k_scan2     <<<8, 256, 0, stream>>>(sumdt, hend, A_log, Hc);
  k_scan3     <<<dim3(NCHUNK,4,4), 128, 0, stream>>>(dtb, ucb, zbuf, xdbl, A_log, Dp, Hc, ybuf);
  k_gemm_out  <<<dim3(144,4), 256, 0, stream>>>(ybuf, out_proj_w, tmp);
  k_scatter   <<<9216, 256, 0, stream>>>(tmp, (float*)d_out);
}

// Round 2
// 357.102 us; speedup vs baseline: 1.4067x; 1.4067x over previous
//
#include <hip/hip_runtime.h>
#include <hip/hip_bf16.h>
#include <cstddef>
#include <cstdint>

#define B_ 4
#define L_ 2305
#define LSEQ 2304
#define NCHUNK 37
#define CHUNK 64
#define ML (B_*L_)

typedef __attribute__((ext_vector_type(8))) short short8;
typedef __attribute__((ext_vector_type(4))) float floatx4;

static __device__ __forceinline__ float sigmoidf_(float x){ return 1.f/(1.f+__expf(-x)); }

static __device__ __forceinline__ void gload16(const void* g, void* l){
  __builtin_amdgcn_global_load_lds((const __attribute__((address_space(1))) unsigned int*)g,
                                   (__attribute__((address_space(3))) unsigned int*)l,
                                   16, 0, 0);
}

// ---------------- cast weights to bf16 ----------------
__global__ __launch_bounds__(256) void k_cast_w(const float* __restrict__ w_in,
                                                const float* __restrict__ w_out,
                                                const float* __restrict__ w_xp,
                                                __hip_bfloat16* __restrict__ a,
                                                __hip_bfloat16* __restrict__ b,
                                                __hip_bfloat16* __restrict__ c){
  int i = blockIdx.x*256 + threadIdx.x;
  if (i < 262144) a[i] = __float2bfloat16(w_in[i]);
  if (i < 131072) b[i] = __float2bfloat16(w_out[i]);
  if (i < 24576)  c[i] = __float2bfloat16(w_xp[i]);
}

// ---------------- K0: build seq (pixel_shuffle + global token) -> bf16 ----------------
__global__ __launch_bounds__(256) void k_build_seq(const float* __restrict__ x,
                                                   const float* __restrict__ gtok,
                                                   __hip_bfloat162* __restrict__ seqb){
  int gid = blockIdx.x*256 + threadIdx.x;           // < ML*128
  int cpair = gid & 127;
  int m = gid >> 7;
  int b = m / L_;
  int t = m - b*L_;
  int c0 = cpair << 1;
  float v0, v1;
  if (t == 0) {
    v0 = gtok[c0]; v1 = gtok[c0+1];
  } else {
    int tt = t - 1;
    int p = tt / 48, q = tt - (tt/48)*48;
    int ch0 = (c0<<2) + ((p&1)<<1) + (q&1);
    size_t base = ((size_t)(b*1024 + ch0)*24 + (p>>1))*24 + (q>>1);
    v0 = x[base];
    v1 = x[base + (size_t)4*24*24];
  }
  __hip_bfloat162 pk;
  pk.x = __float2bfloat16(v0); pk.y = __float2bfloat16(v1);
  seqb[gid] = pk;
}

// ---------------- K1: in_proj MFMA GEMM (M=9220,K=256,N=1024) -> u,z (f32) ----------------
__global__ __launch_bounds__(256) void k_gemm_in_mfma(const ushort* __restrict__ Aseq, // [9220][256] bf16
                                                      const ushort* __restrict__ W,    // [1024][256] bf16
                                                      float* __restrict__ u,
                                                      float* __restrict__ z){
  __shared__ __align__(16) ushort As[128*32];
  __shared__ __align__(16) ushort Bs[128*32];
  int tid = threadIdx.x;
  int wave = tid >> 6, lane = tid & 63;
  int quad = lane >> 4, l16 = lane & 15;
  int row0 = blockIdx.x*128, col0 = blockIdx.y*128;
  int wm = (wave>>1)*64, wn = (wave&1)*64;
  floatx4 acc[4][4];
  #pragma unroll
  for (int i=0;i<4;i++)
    #pragma unroll
    for (int j=0;j<4;j++)
      #pragma unroll
      for (int e=0;e<4;e++) acc[i][j][e] = 0.f;

  for (int k0 = 0; k0 < 256; k0 += 32) {
    #pragma unroll
    for (int t=0;t<2;t++){
      int cid = t*256 + tid;
      int r = cid >> 2, cc = (cid & 3) << 3;
      int ar = row0 + r; if (ar > ML-1) ar = ML-1;
      gload16(Aseq + (size_t)ar*256 + k0 + cc, (char*)As + (t*256 + wave*64)*16);
      gload16(W + (size_t)(col0 + r)*256 + k0 + cc, (char*)Bs + (t*256 + wave*64)*16);
    }
    __syncthreads();
    short8 af[4], bf[4];
    #pragma unroll
    for (int i=0;i<4;i++) af[i] = *(const short8*)(As + (wm + i*16 + l16)*32 + quad*8);
    #pragma unroll
    for (int j=0;j<4;j++) bf[j] = *(const short8*)(Bs + (wn + j*16 + l16)*32 + quad*8);
    #pragma unroll
    for (int i=0;i<4;i++)
      #pragma unroll
      for (int j=0;j<4;j++)
        acc[i][j] = __builtin_amdgcn_mfma_f32_16x16x32_bf16(af[i], bf[j], acc[i][j], 0, 0, 0);
    __syncthreads();
  }
  #pragma unroll
  for (int i=0;i<4;i++){
    #pragma unroll
    for (int r=0;r<4;r++){
      int grow = row0 + wm + i*16 + quad*4 + r;
      if (grow < ML){
        #pragma unroll
        for (int j=0;j<4;j++){
          int gcol = col0 + wn + j*16 + l16;
          float v = acc[i][j][r];
          if (gcol < 512) u[(size_t)grow*512 + gcol] = v;
          else            z[(size_t)grow*512 + gcol - 512] = v;
        }
      }
    }
  }
}

// ---------------- K2: depthwise causal conv(4) + silu (f32 + bf16 shadow) ----------------
__global__ __launch_bounds__(256) void k_conv(const float* __restrict__ u,
                                              const float* __restrict__ cw,
                                              const float* __restrict__ cb,
                                              float* __restrict__ uc,
                                              __hip_bfloat16* __restrict__ uc16){
  int gid = blockIdx.x*256 + threadIdx.x;           // < ML*512
  int d = gid & 511;
  int m = gid >> 9;
  int b = m / L_;
  int l = m - b*L_;
  float4 w = *(const float4*)&cw[d<<2];
  float acc = cb[d];
  const float* up = u + (size_t)m*512 + d;
  if (l >= 3) acc += up[-3*512]*w.x;
  if (l >= 2) acc += up[-2*512]*w.y;
  if (l >= 1) acc += up[-1*512]*w.z;
  acc += up[0]*w.w;
  float v = acc * sigmoidf_(acc);
  uc[gid] = v;
  uc16[gid] = __float2bfloat16(v);
}

// ---------------- K3: x_dbl MFMA GEMM (M=9220,K=512,N=48) ----------------
__global__ __launch_bounds__(256) void k_xdbl_mfma(const ushort* __restrict__ U,  // [9220][512] bf16
                                                   const ushort* __restrict__ Wx, // [48][512] bf16
                                                   float* __restrict__ xdbl){
  __shared__ __align__(16) ushort As[128*32];
  __shared__ __align__(16) ushort Bs[48*32];
  int tid = threadIdx.x;
  int wave = tid >> 6, lane = tid & 63;
  int quad = lane >> 4, l16 = lane & 15;
  int row0 = blockIdx.x*128;
  floatx4 acc[2][3];
  #pragma unroll
  for (int i=0;i<2;i++)
    #pragma unroll
    for (int j=0;j<3;j++)
      #pragma unroll
      for (int e=0;e<4;e++) acc[i][j][e] = 0.f;

  for (int k0 = 0; k0 < 512; k0 += 32) {
    #pragma unroll
    for (int t=0;t<2;t++){
      int cid = t*256 + tid;
      int r = cid >> 2, cc = (cid & 3) << 3;
      int ar = row0 + r; if (ar > ML-1) ar = ML-1;
      gload16(U + (size_t)ar*512 + k0 + cc, (char*)As + (t*256 + wave*64)*16);
    }
    if (wave < 3){
      int cid = wave*64 + lane;
      int r = cid >> 2, cc = (cid & 3) << 3;
      gload16(Wx + (size_t)r*512 + k0 + cc, (char*)Bs + (wave*64)*16);
    }
    __syncthreads();
    short8 af[2], bf[3];
    #pragma unroll
    for (int i=0;i<2;i++) af[i] = *(const short8*)(As + (wave*32 + i*16 + l16)*32 + quad*8);
    #pragma unroll
    for (int j=0;j<3;j++) bf[j] = *(const short8*)(Bs + (j*16 + l16)*32 + quad*8);
    #pragma unroll
    for (int i=0;i<2;i++)
      #pragma unroll
      for (int j=0;j<3;j++)
        acc[i][j] = __builtin_amdgcn_mfma_f32_16x16x32_bf16(af[i], bf[j], acc[i][j], 0, 0, 0);
    __syncthreads();
  }
  #pragma unroll
  for (int i=0;i<2;i++){
    #pragma unroll
    for (int r=0;r<4;r++){
      int grow = row0 + wave*32 + i*16 + quad*4 + r;
      if (grow < ML){
        #pragma unroll
        for (int j=0;j<3;j++){
          xdbl[(size_t)grow*48 + j*16 + l16] = acc[i][j][r];
        }
      }
    }
  }
}

// ---------------- K4: dt = softplus(x_dbl[:, :16] @ dt_proj_w^T + b) ----------------
__global__ __launch_bounds__(256) void k_dt(const float* __restrict__ xdbl,
                                            const float* __restrict__ dpw,
                                            const float* __restrict__ dpb,
                                            float* __restrict__ dt){
  __shared__ float xr[16];
  int m = blockIdx.x;
  int d = blockIdx.y*256 + threadIdx.x;
  if (threadIdx.x < 16) xr[threadIdx.x] = xdbl[(size_t)m*48 + threadIdx.x];
  __syncthreads();
  const float4* wp = (const float4*)&dpw[d<<4];
  float4 w0 = wp[0], w1 = wp[1], w2 = wp[2], w3 = wp[3];
  float acc = dpb[d];
  acc += w0.x*xr[0]  + w0.y*xr[1]  + w0.z*xr[2]  + w0.w*xr[3];
  acc += w1.x*xr[4]  + w1.y*xr[5]  + w1.z*xr[6]  + w1.w*xr[7];
  acc += w2.x*xr[8]  + w2.y*xr[9]  + w2.z*xr[10] + w2.w*xr[11];
  acc += w3.x*xr[12] + w3.y*xr[13] + w3.z*xr[14] + w3.w*xr[15];
  float v = (acc > 20.f) ? acc : log1pf(__expf(acc));
  dt[(size_t)m*512 + d] = v;
}

// ---------------- K5a: chunk-local scan (h_in = 0) ----------------
__global__ __launch_bounds__(128) void k_scan1(const float* __restrict__ dt,
                                               const float* __restrict__ uc,
                                               const float* __restrict__ xdbl,
                                               const float* __restrict__ A_log,
                                               float* __restrict__ sumdt,
                                               float* __restrict__ hend){
  __shared__ float Bsh[CHUNK*16];
  int c = blockIdx.x, b = blockIdx.y, qr = blockIdx.z;
  int d = qr*128 + threadIdx.x;
  int l0 = c*CHUNK;
  int len = min(CHUNK, L_ - l0);
  for (int i = threadIdx.x; i < len*16; i += 128) {
    int ll = i >> 4, n = i & 15;
    Bsh[i] = xdbl[(size_t)(b*L_ + l0 + ll)*48 + 16 + n];
  }
  __syncthreads();
  float A[16];
  #pragma unroll
  for (int g=0; g<4; g++){
    float4 al = *(const float4*)&A_log[(size_t)(d<<4) + g*4];
    A[g*4+0] = -__expf(al.x); A[g*4+1] = -__expf(al.y);
    A[g*4+2] = -__expf(al.z); A[g*4+3] = -__expf(al.w);
  }
  float h[16];
  #pragma unroll
  for (int n=0;n<16;n++) h[n]=0.f;
  float sd = 0.f;
  const float* dtp = dt + (size_t)(b*L_ + l0)*512 + d;
  const float* up  = uc + (size_t)(b*L_ + l0)*512 + d;
  for (int ll=0; ll<len; ll++){
    float dtv = dtp[(size_t)ll*512];
    float uv  = up[(size_t)ll*512];
    sd += dtv;
    float du = dtv*uv;
    const float* bl = &Bsh[ll*16];
    #pragma unroll
    for (int n=0;n<16;n++) h[n] = __expf(dtv*A[n])*h[n] + du*bl[n];
  }
  size_t base = (size_t)(b*512 + d)*NCHUNK + c;
  sumdt[base] = sd;
  #pragma unroll
  for (int n=0;n<16;n++) hend[base*16 + n] = h[n];
}

// ---------------- K5b: inter-chunk scan (37 steps per (b,d)) ----------------
__global__ __launch_bounds__(256) void k_scan2(const float* __restrict__ sumdt,
                                               const float* __restrict__ hend,
                                               const float* __restrict__ A_log,
                                               float* __restrict__ Hc){
  int idx = blockIdx.x*256 + threadIdx.x;   // < 2048
  int b = idx >> 9, d = idx & 511;
  float A[16];
  #pragma unroll
  for (int g=0; g<4; g++){
    float4 al = *(const float4*)&A_log[(size_t)(d<<4) + g*4];
    A[g*4+0] = -__expf(al.x); A[g*4+1] = -__expf(al.y);
    A[g*4+2] = -__expf(al.z); A[g*4+3] = -__expf(al.w);
  }
  float H[16];
  #pragma unroll
  for (int n=0;n<16;n++) H[n]=0.f;
  size_t rb = (size_t)(b*512+d)*NCHUNK;
  for (int c=0;c<NCHUNK;c++){
    size_t base = (rb + c)*16;
    #pragma unroll
    for (int n=0;n<16;n++) Hc[base+n] = H[n];
    float s = sumdt[rb + c];
    #pragma unroll
    for (int n=0;n<16;n++) H[n] = __expf(A[n]*s)*H[n] + hend[base+n];
  }
}

// ---------------- K5c: chunk replay with carry + fused epilogue -> y (bf16) ----------------
__global__ __launch_bounds__(128) void k_scan3(const float* __restrict__ dt,
                                               const float* __restrict__ uc,
                                               const float* __restrict__ zb,
                                               const float* __restrict__ xdbl,
                                               const float* __restrict__ A_log,
                                               const float* __restrict__ Dp,
                                               const float* __restrict__ Hc,
                                               __hip_bfloat16* __restrict__ y){
  __shared__ float Bsh[CHUNK*16];
  __shared__ float Csh[CHUNK*16];
  int c = blockIdx.x, b = blockIdx.y, qr = blockIdx.z;
  int d = qr*128 + threadIdx.x;
  int l0 = c*CHUNK;
  int len = min(CHUNK, L_ - l0);
  for (int i = threadIdx.x; i < len*16; i += 128) {
    int ll = i >> 4, n = i & 15;
    size_t rowb = (size_t)(b*L_ + l0 + ll)*48;
    Bsh[i] = xdbl[rowb + 16 + n];
    Csh[i] = xdbl[rowb + 32 + n];
  }
  __syncthreads();
  float A[16];
  #pragma unroll
  for (int g=0; g<4; g++){
    float4 al = *(const float4*)&A_log[(size_t)(d<<4) + g*4];
    A[g*4+0] = -__expf(al.x); A[g*4+1] = -__expf(al.y);
    A[g*4+2] = -__expf(al.z); A[g*4+3] = -__expf(al.w);
  }
  float h[16];
  size_t cb = ((size_t)(b*512+d)*NCHUNK + c)*16;
  #pragma unroll
  for (int n=0;n<16;n++) h[n] = Hc[cb+n];
  float Dd = Dp[d];
  size_t off = (size_t)(b*L_ + l0)*512 + d;
  for (int ll=0; ll<len; ll++){
    float dtv = dt[off + (size_t)ll*512];
    float uv  = uc[off + (size_t)ll*512];
    float du = dtv*uv;
    float yv = 0.f;
    const float* bl = &Bsh[ll*16];
    const float* cl = &Csh[ll*16];
    #pragma unroll
    for (int n=0;n<16;n++){
      h[n] = __expf(dtv*A[n])*h[n] + du*bl[n];
      yv += h[n]*cl[n];
    }
    float zv = zb[off + (size_t)ll*512];
    y[off + (size_t)ll*512] = __float2bfloat16((yv + uv*Dd) * (zv * sigmoidf_(zv)));
  }
}

// ---------------- K6: out_proj MFMA GEMM (M=9216,K=512,N=256), skip token 0 ----------------
__global__ __launch_bounds__(256) void k_gemm_out_mfma(const ushort* __restrict__ Y,  // [9220][512] bf16
                                                       const ushort* __restrict__ W,  // [256][512] bf16
                                                       float* __restrict__ tmp){
  __shared__ __align__(16) ushort As[128*32];
  __shared__ __align__(16) ushort Bs[128*32];
  int tid = threadIdx.x;
  int wave = tid >> 6, lane = tid & 63;
  int quad = lane >> 4, l16 = lane & 15;
  int row0 = blockIdx.x*128, col0 = blockIdx.y*128;
  int b = row0 / LSEQ;                     // tiles never cross batch (2304 % 128 == 0)
  int arow0 = b*L_ + 1 + (row0 - b*LSEQ);
  int wm = (wave>>1)*64, wn = (wave&1)*64;
  floatx4 acc[4][4];
  #pragma unroll
  for (int i=0;i<4;i++)
    #pragma unroll
    for (int j=0;j<4;j++)
      #pragma unroll
      for (int e=0;e<4;e++) acc[i][j][e] = 0.f;

  for (int k0 = 0; k0 < 512; k0 += 32) {
    #pragma unroll
    for (int t=0;t<2;t++){
      int cid = t*256 + tid;
      int r = cid >> 2, cc = (cid & 3) << 3;
      gload16(Y + (size_t)(arow0 + r)*512 + k0 + cc, (char*)As + (t*256 + wave*64)*16);
      gload16(W + (size_t)(col0 + r)*512 + k0 + cc, (char*)Bs + (t*256 + wave*64)*16);
    }
    __syncthreads();
    short8 af[4], bf[4];
    #pragma unroll
    for (int i=0;i<4;i++) af[i] = *(const short8*)(As + (wm + i*16 + l16)*32 + quad*8);
    #pragma unroll
    for (int j=0;j<4;j++) bf[j] = *(const short8*)(Bs + (wn + j*16 + l16)*32 + quad*8);
    #pragma unroll
    for (int i=0;i<4;i++)
      #pragma unroll
      for (int j=0;j<4;j++)
        acc[i][j] = __builtin_amdgcn_mfma_f32_16x16x32_bf16(af[i], bf[j], acc[i][j], 0, 0, 0);
    __syncthreads();
  }
  #pragma unroll
  for (int i=0;i<4;i++){
    #pragma unroll
    for (int r=0;r<4;r++){
      size_t rr = (size_t)(row0 + wm + i*16 + quad*4 + r)*256;
      #pragma unroll
      for (int j=0;j<4;j++){
        tmp[rr + col0 + wn + j*16 + l16] = acc[i][j][r];
      }
    }
  }
}

// ---------------- K7: pixel_unshuffle scatter (coalesced writes) ----------------
__global__ __launch_bounds__(256) void k_scatter(const float* __restrict__ tmp,
                                                 float* __restrict__ out){
  int gid = blockIdx.x*256 + threadIdx.x;   // < 4*1024*24*24
  int w = gid % 24;
  int t1 = gid / 24;
  int h = t1 % 24;
  int t2 = t1 / 24;
  int co = t2 & 1023;
  int b = t2 >> 10;
  int c = co >> 2;
  int i = (co >> 1) & 1;
  int j = co & 1;
  int p = (h<<1) + i, q = (w<<1) + j;
  int t = p*48 + q;
  out[gid] = tmp[(size_t)(b*LSEQ + t)*256 + c];
}

extern "C" void kernel_launch(void* const* d_in, const int* in_sizes, int n_in,
                              void* d_out, int out_size, void* d_ws, size_t ws_size,
                              hipStream_t stream) {
  const float* x          = (const float*)d_in[0];
  const float* gtok       = (const float*)d_in[1];
  const float* in_proj_w  = (const float*)d_in[2];
  const float* conv_w     = (const float*)d_in[3];
  const float* conv_b     = (const float*)d_in[4];
  const float* x_proj_w   = (const float*)d_in[5];
  const float* dt_proj_w  = (const float*)d_in[6];
  const float* dt_proj_b  = (const float*)d_in[7];
  const float* A_log      = (const float*)d_in[8];
  const float* Dp         = (const float*)d_in[9];
  const float* out_proj_w = (const float*)d_in[10];

  float* ws = (float*)d_ws;
  float* seqb_f = ws;                                   // ML*256 bf16 = ML*128 floats
  float* ubuf   = seqb_f + (size_t)ML*128;              // ML*512 f32
  float* zbuf   = ubuf   + (size_t)ML*512;
  float* ucb    = zbuf   + (size_t)ML*512;
  float* ucb16_f= ucb    + (size_t)ML*512;              // ML*512 bf16 = ML*256 floats
  float* xdbl   = ucb16_f+ (size_t)ML*256;              // ML*48 f32
  float* win16_f= xdbl   + (size_t)ML*48;               // 262144 bf16 = 131072 floats
  float* wout16_f= win16_f + 131072;                    // 131072 bf16 = 65536 floats
  float* wxp16_f = wout16_f + 65536;                    // 24576 bf16 = 12288 floats
  float* sumdt  = wxp16_f + 12288;                      // B*512*NCHUNK
  float* hend   = sumdt + (size_t)B_*512*NCHUNK;        // *16
  float* Hc     = hend  + (size_t)B_*512*NCHUNK*16;     // *16
  float* ybuf_f = Hc    + (size_t)B_*512*NCHUNK*16;     // ML*512 bf16 = ML*256 floats
  float* dtb    = ubuf;            // reuse: pre-conv u dead after k_conv
  float* tmp    = sumdt;           // reuse: sumdt/hend/Hc dead after k_scan3 (2.50M >= 2.36M floats)

  __hip_bfloat16* seqb  = (__hip_bfloat16*)seqb_f;
  __hip_bfloat16* ucb16 = (__hip_bfloat16*)ucb16_f;
  __hip_bfloat16* win16 = (__hip_bfloat16*)win16_f;
  __hip_bfloat16* wout16= (__hip_bfloat16*)wout16_f;
  __hip_bfloat16* wxp16 = (__hip_bfloat16*)wxp16_f;
  __hip_bfloat16* ybuf  = (__hip_bfloat16*)ybuf_f;

  k_cast_w      <<<1024, 256, 0, stream>>>(in_proj_w, out_proj_w, x_proj_w, win16, wout16, wxp16);
  k_build_seq   <<<4610, 256, 0, stream>>>(x, gtok, (__hip_bfloat162*)seqb);
  k_gemm_in_mfma<<<dim3(73,8), 256, 0, stream>>>((const ushort*)seqb, (const ushort*)win16, ubuf, zbuf);
  k_conv        <<<18440, 256, 0, stream>>>(ubuf, conv_w, conv_b, ucb, ucb16);
  k_xdbl_mfma   <<<73, 256, 0, stream>>>((const ushort*)ucb16, (const ushort*)wxp16, xdbl);
  k_dt          <<<dim3(9220,2), 256, 0, stream>>>(xdbl, dt_proj_w, dt_proj_b, dtb);
  k_scan1       <<<dim3(NCHUNK,4,4), 128, 0, stream>>>(dtb, ucb, xdbl, A_log, sumdt, hend);
  k_scan2       <<<8, 256, 0, stream>>>(sumdt, hend, A_log, Hc);
  k_scan3       <<<dim3(NCHUNK,4,4), 128, 0, stream>>>(dtb, ucb, zbuf, xdbl, A_log, Dp, Hc, ybuf);
  k_gemm_out_mfma<<<dim3(72,2), 256, 0, stream>>>((const ushort*)ybuf, (const ushort*)wout16, tmp);
  k_scatter     <<<9216, 256, 0, stream>>>(tmp, (float*)d_out);
}

// Round 3
// 261.458 us; speedup vs baseline: 1.9213x; 1.3658x over previous
//
#include <hip/hip_runtime.h>
#include <hip/hip_bf16.h>
#include <cstddef>
#include <cstdint>

#define B_ 4
#define L_ 2305
#define LSEQ 2304
#define CHUNK 32
#define NCHUNK 73        // 72 full chunks + 1 tail (len=1)
#define NC1 72           // full chunks (scan1 domain; hend/sumdt/Hc domain)
#define ML (B_*L_)

typedef __attribute__((ext_vector_type(8))) short short8;
typedef __attribute__((ext_vector_type(4))) float floatx4;

static __device__ __forceinline__ float sigmoidf_(float x){ return 1.f/(1.f+__expf(-x)); }

static __device__ __forceinline__ ushort f2bf(float v){
  __hip_bfloat16 b = __float2bfloat16(v);
  return *reinterpret_cast<ushort*>(&b);
}

static __device__ __forceinline__ void gload16(const void* g, void* l){
  __builtin_amdgcn_global_load_lds((const __attribute__((address_space(1))) unsigned int*)g,
                                   (__attribute__((address_space(3))) unsigned int*)l,
                                   16, 0, 0);
}

// ---------------- cast weights to bf16 ----------------
__global__ __launch_bounds__(256) void k_cast_w(const float* __restrict__ w_in,
                                                const float* __restrict__ w_out,
                                                const float* __restrict__ w_xp,
                                                __hip_bfloat16* __restrict__ a,
                                                __hip_bfloat16* __restrict__ b,
                                                __hip_bfloat16* __restrict__ c){
  int i = blockIdx.x*256 + threadIdx.x;
  if (i < 262144) a[i] = __float2bfloat16(w_in[i]);
  if (i < 131072) b[i] = __float2bfloat16(w_out[i]);
  if (i < 24576)  c[i] = __float2bfloat16(w_xp[i]);
}

// ---------------- K0: build seq (pixel_shuffle + global token) -> bf16 ----------------
__global__ __launch_bounds__(256) void k_build_seq(const float* __restrict__ x,
                                                   const float* __restrict__ gtok,
                                                   __hip_bfloat162* __restrict__ seqb){
  int gid = blockIdx.x*256 + threadIdx.x;           // < ML*128
  int cpair = gid & 127;
  int m = gid >> 7;
  int b = m / L_;
  int t = m - b*L_;
  int c0 = cpair << 1;
  float v0, v1;
  if (t == 0) {
    v0 = gtok[c0]; v1 = gtok[c0+1];
  } else {
    int tt = t - 1;
    int p = tt / 48, q = tt - (tt/48)*48;
    int ch0 = (c0<<2) + ((p&1)<<1) + (q&1);
    size_t base = ((size_t)(b*1024 + ch0)*24 + (p>>1))*24 + (q>>1);
    v0 = x[base];
    v1 = x[base + (size_t)4*24*24];
  }
  __hip_bfloat162 pk;
  pk.x = __float2bfloat16(v0); pk.y = __float2bfloat16(v1);
  seqb[gid] = pk;
}

// ---------------- K1: in_proj MFMA GEMM (M=9220,K=256,N=1024) -> u,z (f32) ----------------
__global__ __launch_bounds__(256) void k_gemm_in_mfma(const ushort* __restrict__ Aseq,
                                                      const ushort* __restrict__ W,
                                                      float* __restrict__ u,
                                                      float* __restrict__ z){
  __shared__ __align__(16) ushort As[128*32];
  __shared__ __align__(16) ushort Bs[128*32];
  int tid = threadIdx.x;
  int wave = tid >> 6, lane = tid & 63;
  int quad = lane >> 4, l16 = lane & 15;
  int row0 = blockIdx.x*128, col0 = blockIdx.y*128;
  int wm = (wave>>1)*64, wn = (wave&1)*64;
  floatx4 acc[4][4];
  #pragma unroll
  for (int i=0;i<4;i++)
    #pragma unroll
    for (int j=0;j<4;j++)
      #pragma unroll
      for (int e=0;e<4;e++) acc[i][j][e] = 0.f;

  for (int k0 = 0; k0 < 256; k0 += 32) {
    #pragma unroll
    for (int t=0;t<2;t++){
      int cid = t*256 + tid;
      int r = cid >> 2, cc = (cid & 3) << 3;
      int ar = row0 + r; if (ar > ML-1) ar = ML-1;
      gload16(Aseq + (size_t)ar*256 + k0 + cc, (char*)As + (t*256 + wave*64)*16);
      gload16(W + (size_t)(col0 + r)*256 + k0 + cc, (char*)Bs + (t*256 + wave*64)*16);
    }
    __syncthreads();
    short8 af[4], bf[4];
    #pragma unroll
    for (int i=0;i<4;i++) af[i] = *(const short8*)(As + (wm + i*16 + l16)*32 + quad*8);
    #pragma unroll
    for (int j=0;j<4;j++) bf[j] = *(const short8*)(Bs + (wn + j*16 + l16)*32 + quad*8);
    #pragma unroll
    for (int i=0;i<4;i++)
      #pragma unroll
      for (int j=0;j<4;j++)
        acc[i][j] = __builtin_amdgcn_mfma_f32_16x16x32_bf16(af[i], bf[j], acc[i][j], 0, 0, 0);
    __syncthreads();
  }
  #pragma unroll
  for (int i=0;i<4;i++){
    #pragma unroll
    for (int r=0;r<4;r++){
      int grow = row0 + wm + i*16 + quad*4 + r;
      if (grow < ML){
        #pragma unroll
        for (int j=0;j<4;j++){
          int gcol = col0 + wn + j*16 + l16;
          float v = acc[i][j][r];
          if (gcol < 512) u[(size_t)grow*512 + gcol] = v;
          else            z[(size_t)grow*512 + gcol - 512] = v;
        }
      }
    }
  }
}

// ---------------- K2: depthwise causal conv(4) + silu, float4 (f32 + bf16 shadow) ----------------
__global__ __launch_bounds__(256) void k_conv(const float4* __restrict__ u4,
                                              const float4* __restrict__ cw4,
                                              const float4* __restrict__ cb4,
                                              float4* __restrict__ uc4,
                                              ushort4* __restrict__ uc16_4){
  int gid = blockIdx.x*256 + threadIdx.x;           // < ML*128
  int dq = gid & 127;
  int m = gid >> 7;
  int b = m / L_;
  int l = m - b*L_;
  float4 w0 = cw4[dq*4+0], w1 = cw4[dq*4+1], w2 = cw4[dq*4+2], w3 = cw4[dq*4+3];
  float4 acc = cb4[dq];
  const float4* up = u4 + (size_t)m*128 + dq;
  float4 t;
  if (l >= 3){ t = up[-3*128]; acc.x += t.x*w0.x; acc.y += t.y*w1.x; acc.z += t.z*w2.x; acc.w += t.w*w3.x; }
  if (l >= 2){ t = up[-2*128]; acc.x += t.x*w0.y; acc.y += t.y*w1.y; acc.z += t.z*w2.y; acc.w += t.w*w3.y; }
  if (l >= 1){ t = up[-1*128]; acc.x += t.x*w0.z; acc.y += t.y*w1.z; acc.z += t.z*w2.z; acc.w += t.w*w3.z; }
  t = up[0]; acc.x += t.x*w0.w; acc.y += t.y*w1.w; acc.z += t.z*w2.w; acc.w += t.w*w3.w;
  float4 v;
  v.x = acc.x * sigmoidf_(acc.x);
  v.y = acc.y * sigmoidf_(acc.y);
  v.z = acc.z * sigmoidf_(acc.z);
  v.w = acc.w * sigmoidf_(acc.w);
  uc4[gid] = v;
  ushort4 pk; pk.x = f2bf(v.x); pk.y = f2bf(v.y); pk.z = f2bf(v.z); pk.w = f2bf(v.w);
  uc16_4[gid] = pk;
}

// ---------------- K3: x_dbl MFMA GEMM (M=9220,K=512,N=48) ----------------
__global__ __launch_bounds__(256) void k_xdbl_mfma(const ushort* __restrict__ U,
                                                   const ushort* __restrict__ Wx,
                                                   float* __restrict__ xdbl){
  __shared__ __align__(16) ushort As[128*32];
  __shared__ __align__(16) ushort Bs[48*32];
  int tid = threadIdx.x;
  int wave = tid >> 6, lane = tid & 63;
  int quad = lane >> 4, l16 = lane & 15;
  int row0 = blockIdx.x*128;
  floatx4 acc[2][3];
  #pragma unroll
  for (int i=0;i<2;i++)
    #pragma unroll
    for (int j=0;j<3;j++)
      #pragma unroll
      for (int e=0;e<4;e++) acc[i][j][e] = 0.f;

  for (int k0 = 0; k0 < 512; k0 += 32) {
    #pragma unroll
    for (int t=0;t<2;t++){
      int cid = t*256 + tid;
      int r = cid >> 2, cc = (cid & 3) << 3;
      int ar = row0 + r; if (ar > ML-1) ar = ML-1;
      gload16(U + (size_t)ar*512 + k0 + cc, (char*)As + (t*256 + wave*64)*16);
    }
    if (wave < 3){
      int cid = wave*64 + lane;
      int r = cid >> 2, cc = (cid & 3) << 3;
      gload16(Wx + (size_t)r*512 + k0 + cc, (char*)Bs + (wave*64)*16);
    }
    __syncthreads();
    short8 af[2], bf[3];
    #pragma unroll
    for (int i=0;i<2;i++) af[i] = *(const short8*)(As + (wave*32 + i*16 + l16)*32 + quad*8);
    #pragma unroll
    for (int j=0;j<3;j++) bf[j] = *(const short8*)(Bs + (j*16 + l16)*32 + quad*8);
    #pragma unroll
    for (int i=0;i<2;i++)
      #pragma unroll
      for (int j=0;j<3;j++)
        acc[i][j] = __builtin_amdgcn_mfma_f32_16x16x32_bf16(af[i], bf[j], acc[i][j], 0, 0, 0);
    __syncthreads();
  }
  #pragma unroll
  for (int i=0;i<2;i++){
    #pragma unroll
    for (int r=0;r<4;r++){
      int grow = row0 + wave*32 + i*16 + quad*4 + r;
      if (grow < ML){
        #pragma unroll
        for (int j=0;j<3;j++){
          xdbl[(size_t)grow*48 + j*16 + l16] = acc[i][j][r];
        }
      }
    }
  }
}

// ---------------- K4: dt = softplus(x_dbl[:, :16] @ dt_proj_w^T + b) ----------------
__global__ __launch_bounds__(256) void k_dt(const float* __restrict__ xdbl,
                                            const float* __restrict__ dpw,
                                            const float* __restrict__ dpb,
                                            float* __restrict__ dt){
  __shared__ float xr[16];
  int m = blockIdx.x;
  int d = blockIdx.y*256 + threadIdx.x;
  if (threadIdx.x < 16) xr[threadIdx.x] = xdbl[(size_t)m*48 + threadIdx.x];
  __syncthreads();
  const float4* wp = (const float4*)&dpw[d<<4];
  float4 w0 = wp[0], w1 = wp[1], w2 = wp[2], w3 = wp[3];
  float acc = dpb[d];
  acc += w0.x*xr[0]  + w0.y*xr[1]  + w0.z*xr[2]  + w0.w*xr[3];
  acc += w1.x*xr[4]  + w1.y*xr[5]  + w1.z*xr[6]  + w1.w*xr[7];
  acc += w2.x*xr[8]  + w2.y*xr[9]  + w2.z*xr[10] + w2.w*xr[11];
  acc += w3.x*xr[12] + w3.y*xr[13] + w3.z*xr[14] + w3.w*xr[15];
  float v = (acc > 20.f) ? acc : log1pf(__expf(acc));
  dt[(size_t)m*512 + d] = v;
}

// ---------------- K5a: chunk-local scan, full chunks only, fully unrolled ----------------
__global__ __launch_bounds__(128) void k_scan1(const float* __restrict__ dt,
                                               const float* __restrict__ uc,
                                               const float* __restrict__ xdbl,
                                               const float* __restrict__ A_log,
                                               float* __restrict__ sumdt,
                                               float* __restrict__ hend){
  __shared__ float Bsh[CHUNK*16];
  int c = blockIdx.x, b = blockIdx.y, qr = blockIdx.z;
  int d = (qr<<7) + threadIdx.x;
  int l0 = c*CHUNK;
  // preload dt/u for all 32 steps (coalesced, max MLP) before the barrier
  float dtv[CHUNK], uv[CHUNK];
  const float* dtp = dt + (size_t)(b*L_ + l0)*512 + d;
  const float* up  = uc + (size_t)(b*L_ + l0)*512 + d;
  #pragma unroll
  for (int ll=0; ll<CHUNK; ll++){ dtv[ll] = dtp[(size_t)ll*512]; uv[ll] = up[(size_t)ll*512]; }
  float A[16];
  #pragma unroll
  for (int g=0; g<4; g++){
    float4 al = *(const float4*)&A_log[(size_t)(d<<4) + g*4];
    A[g*4+0] = -__expf(al.x); A[g*4+1] = -__expf(al.y);
    A[g*4+2] = -__expf(al.z); A[g*4+3] = -__expf(al.w);
  }
  for (int i = threadIdx.x; i < CHUNK*16; i += 128) {
    int ll = i >> 4, n = i & 15;
    Bsh[i] = xdbl[(size_t)(b*L_ + l0 + ll)*48 + 16 + n];
  }
  __syncthreads();
  float h[16];
  #pragma unroll
  for (int n=0;n<16;n++) h[n]=0.f;
  float sd = 0.f;
  #pragma unroll
  for (int ll=0; ll<CHUNK; ll++){
    sd += dtv[ll];
    float du = dtv[ll]*uv[ll];
    const float* bl = &Bsh[ll<<4];
    #pragma unroll
    for (int n=0;n<16;n++) h[n] = __expf(dtv[ll]*A[n])*h[n] + du*bl[n];
  }
  sumdt[((c<<2)+b)*512 + d] = sd;
  float* hp = hend + ((size_t)((c<<2)+b)*512 + d)*16;
  #pragma unroll
  for (int g=0;g<4;g++) *(float4*)(hp + g*4) = make_float4(h[g*4],h[g*4+1],h[g*4+2],h[g*4+3]);
}

// ---------------- K5b: inter-chunk scan, parallel over (b,d,n) ----------------
__global__ __launch_bounds__(256) void k_scan2(const float* __restrict__ sumdt,
                                               const float* __restrict__ hend,
                                               const float* __restrict__ A_log,
                                               float* __restrict__ Hc){
  int idx = blockIdx.x*256 + threadIdx.x;   // < 32768
  int n = idx & 15, d = (idx>>4) & 511, b = idx >> 13;
  float An = -__expf(A_log[(d<<4)+n]);
  float H = 0.f;
  #pragma unroll 4
  for (int c=0; c<NC1; c++){
    size_t base = ((size_t)((c<<2)+b)*512 + d)*16 + n;
    H = __expf(An*sumdt[((c<<2)+b)*512 + d])*H + hend[base];
    Hc[base] = H;                     // carry INTO chunk c+1
  }
}

// ---------------- K5c: chunk replay with carry + fused epilogue -> y (bf16) ----------------
__global__ __launch_bounds__(128) void k_scan3(const float* __restrict__ dt,
                                               const float* __restrict__ uc,
                                               const float* __restrict__ zb,
                                               const float* __restrict__ xdbl,
                                               const float* __restrict__ A_log,
                                               const float* __restrict__ Dp,
                                               const float* __restrict__ Hc,
                                               __hip_bfloat16* __restrict__ y){
  __shared__ float Bsh[CHUNK*16];
  __shared__ float Csh[CHUNK*16];
  int c = blockIdx.x, b = blockIdx.y, qr = blockIdx.z;
  int d = (qr<<7) + threadIdx.x;
  int l0 = c*CHUNK;
  int len = min(CHUNK, L_ - l0);
  size_t off = (size_t)(b*L_ + l0)*512 + d;
  // preload all inputs before the barrier
  float dtv[CHUNK], uv[CHUNK], zv[CHUNK];
  #pragma unroll
  for (int ll=0; ll<CHUNK; ll++){
    int o = min(ll, len-1);
    bool ok = ll < len;
    float a = dt[off + (size_t)o*512];
    float u = uc[off + (size_t)o*512];
    float zz= zb[off + (size_t)o*512];
    dtv[ll] = ok ? a : 0.f;
    uv[ll]  = ok ? u : 0.f;
    zv[ll]  = ok ? zz: 0.f;
  }
  float A[16];
  #pragma unroll
  for (int g=0; g<4; g++){
    float4 al = *(const float4*)&A_log[(size_t)(d<<4) + g*4];
    A[g*4+0] = -__expf(al.x); A[g*4+1] = -__expf(al.y);
    A[g*4+2] = -__expf(al.z); A[g*4+3] = -__expf(al.w);
  }
  float h[16];
  if (c == 0){
    #pragma unroll
    for (int n=0;n<16;n++) h[n] = 0.f;
  } else {
    const float* hp = Hc + ((size_t)(((c-1)<<2)+b)*512 + d)*16;
    #pragma unroll
    for (int g=0;g<4;g++){
      float4 hv = *(const float4*)(hp + g*4);
      h[g*4]=hv.x; h[g*4+1]=hv.y; h[g*4+2]=hv.z; h[g*4+3]=hv.w;
    }
  }
  for (int i = threadIdx.x; i < CHUNK*16; i += 128) {
    int ll = i >> 4, n = i & 15;
    int l = min(l0 + ll, L_-1);
    size_t rowb = (size_t)(b*L_ + l)*48;
    Bsh[i] = xdbl[rowb + 16 + n];
    Csh[i] = xdbl[rowb + 32 + n];
  }
  __syncthreads();
  float Dd = Dp[d];
  #pragma unroll
  for (int ll=0; ll<CHUNK; ll++){
    float du = dtv[ll]*uv[ll];
    float yv = 0.f;
    const float* bl = &Bsh[ll<<4];
    const float* cl = &Csh[ll<<4];
    #pragma unroll
    for (int n=0;n<16;n++){
      h[n] = __expf(dtv[ll]*A[n])*h[n] + du*bl[n];
      yv += h[n]*cl[n];
    }
    if (ll < len){
      float z = zv[ll];
      y[off + (size_t)ll*512] = __float2bfloat16((yv + uv[ll]*Dd) * (z * sigmoidf_(z)));
    }
  }
}

// ---------------- K6: out_proj MFMA GEMM (M=9216,K=512,N=256), skip token 0 ----------------
__global__ __launch_bounds__(256) void k_gemm_out_mfma(const ushort* __restrict__ Y,
                                                       const ushort* __restrict__ W,
                                                       float* __restrict__ tmp){
  __shared__ __align__(16) ushort As[128*32];
  __shared__ __align__(16) ushort Bs[128*32];
  int tid = threadIdx.x;
  int wave = tid >> 6, lane = tid & 63;
  int quad = lane >> 4, l16 = lane & 15;
  int row0 = blockIdx.x*128, col0 = blockIdx.y*128;
  int b = row0 / LSEQ;
  int arow0 = b*L_ + 1 + (row0 - b*LSEQ);
  int wm = (wave>>1)*64, wn = (wave&1)*64;
  floatx4 acc[4][4];
  #pragma unroll
  for (int i=0;i<4;i++)
    #pragma unroll
    for (int j=0;j<4;j++)
      #pragma unroll
      for (int e=0;e<4;e++) acc[i][j][e] = 0.f;

  for (int k0 = 0; k0 < 512; k0 += 32) {
    #pragma unroll
    for (int t=0;t<2;t++){
      int cid = t*256 + tid;
      int r = cid >> 2, cc = (cid & 3) << 3;
      gload16(Y + (size_t)(arow0 + r)*512 + k0 + cc, (char*)As + (t*256 + wave*64)*16);
      gload16(W + (size_t)(col0 + r)*512 + k0 + cc, (char*)Bs + (t*256 + wave*64)*16);
    }
    __syncthreads();
    short8 af[4], bf[4];
    #pragma unroll
    for (int i=0;i<4;i++) af[i] = *(const short8*)(As + (wm + i*16 + l16)*32 + quad*8);
    #pragma unroll
    for (int j=0;j<4;j++) bf[j] = *(const short8*)(Bs + (wn + j*16 + l16)*32 + quad*8);
    #pragma unroll
    for (int i=0;i<4;i++)
      #pragma unroll
      for (int j=0;j<4;j++)
        acc[i][j] = __builtin_amdgcn_mfma_f32_16x16x32_bf16(af[i], bf[j], acc[i][j], 0, 0, 0);
    __syncthreads();
  }
  #pragma unroll
  for (int i=0;i<4;i++){
    #pragma unroll
    for (int r=0;r<4;r++){
      size_t rr = (size_t)(row0 + wm + i*16 + quad*4 + r)*256;
      #pragma unroll
      for (int j=0;j<4;j++){
        tmp[rr + col0 + wn + j*16 + l16] = acc[i][j][r];
      }
    }
  }
}

// ---------------- K7: pixel_unshuffle scatter (coalesced writes) ----------------
__global__ __launch_bounds__(256) void k_scatter(const float* __restrict__ tmp,
                                                 float* __restrict__ out){
  int gid = blockIdx.x*256 + threadIdx.x;   // < 4*1024*24*24
  int w = gid % 24;
  int t1 = gid / 24;
  int h = t1 % 24;
  int t2 = t1 / 24;
  int co = t2 & 1023;
  int b = t2 >> 10;
  int c = co >> 2;
  int i = (co >> 1) & 1;
  int j = co & 1;
  int p = (h<<1) + i, q = (w<<1) + j;
  int t = p*48 + q;
  out[gid] = tmp[(size_t)(b*LSEQ + t)*256 + c];
}

extern "C" void kernel_launch(void* const* d_in, const int* in_sizes, int n_in,
                              void* d_out, int out_size, void* d_ws, size_t ws_size,
                              hipStream_t stream) {
  const float* x          = (const float*)d_in[0];
  const float* gtok       = (const float*)d_in[1];
  const float* in_proj_w  = (const float*)d_in[2];
  const float* conv_w     = (const float*)d_in[3];
  const float* conv_b     = (const float*)d_in[4];
  const float* x_proj_w   = (const float*)d_in[5];
  const float* dt_proj_w  = (const float*)d_in[6];
  const float* dt_proj_b  = (const float*)d_in[7];
  const float* A_log      = (const float*)d_in[8];
  const float* Dp         = (const float*)d_in[9];
  const float* out_proj_w = (const float*)d_in[10];

  float* ws = (float*)d_ws;
  float* seqb_f  = ws;                                  // ML*128 = 1,180,160
  float* ubuf    = seqb_f + (size_t)ML*128;             // ML*512 (dt after k_dt)
  float* zbuf    = ubuf   + (size_t)ML*512;
  float* ucb     = zbuf   + (size_t)ML*512;
  float* ucb16_f = ucb    + (size_t)ML*512;             // ML*256 ; Hc aliases (dead after xdbl)
  float* xdbl    = ucb16_f+ (size_t)ML*256;             // ML*48
  float* win16_f = xdbl   + (size_t)ML*48;              // 131,072
  float* wout16_f= win16_f + 131072;                    // 65,536
  float* wxp16_f = wout16_f + 65536;                    // 12,288
  float* sumdt   = wxp16_f + 12288;                     // NC1*4*512 = 147,456
  float* hend    = sumdt + (size_t)NC1*B_*512;          // NC1*4*512*16 = 2,359,296
  float* ybuf_f  = hend  + (size_t)NC1*B_*512*16;       // ML*256
  float* dtb     = ubuf;            // reuse: pre-conv u dead after k_conv
  float* Hc      = ucb16_f;         // reuse: ucb16 dead after k_xdbl (2,359,296 <= 2,360,320)
  float* tmp     = sumdt;           // reuse: sumdt+hend dead after k_scan2/3 (2,359,296 <= 2,506,752)

  __hip_bfloat16* seqb  = (__hip_bfloat16*)seqb_f;
  __hip_bfloat16* ucb16 = (__hip_bfloat16*)ucb16_f;
  __hip_bfloat16* win16 = (__hip_bfloat16*)win16_f;
  __hip_bfloat16* wout16= (__hip_bfloat16*)wout16_f;
  __hip_bfloat16* wxp16 = (__hip_bfloat16*)wxp16_f;
  __hip_bfloat16* ybuf  = (__hip_bfloat16*)ybuf_f;

  k_cast_w      <<<1024, 256, 0, stream>>>(in_proj_w, out_proj_w, x_proj_w, win16, wout16, wxp16);
  k_build_seq   <<<4610, 256, 0, stream>>>(x, gtok, (__hip_bfloat162*)seqb);
  k_gemm_in_mfma<<<dim3(73,8), 256, 0, stream>>>((const ushort*)seqb, (const ushort*)win16, ubuf, zbuf);
  k_conv        <<<4610, 256, 0, stream>>>((const float4*)ubuf, (const float4*)conv_w,
                                           (const float4*)conv_b, (float4*)ucb, (ushort4*)ucb16);
  k_xdbl_mfma   <<<73, 256, 0, stream>>>((const ushort*)ucb16, (const ushort*)wxp16, xdbl);
  k_dt          <<<dim3(9220,2), 256, 0, stream>>>(xdbl, dt_proj_w, dt_proj_b, dtb);
  k_scan1       <<<dim3(NC1,4,4), 128, 0, stream>>>(dtb, ucb, xdbl, A_log, sumdt, hend);
  k_scan2       <<<128, 256, 0, stream>>>(sumdt, hend, A_log, Hc);
  k_scan3       <<<dim3(NCHUNK,4,4), 128, 0, stream>>>(dtb, ucb, zbuf, xdbl, A_log, Dp, Hc, ybuf);
  k_gemm_out_mfma<<<dim3(72,2), 256, 0, stream>>>((const ushort*)ybuf, (const ushort*)wout16, tmp);
  k_scatter     <<<9216, 256, 0, stream>>>(tmp, (float*)d_out);
}